// Round 5
// baseline (123.516 us; speedup 1.0000x reference)
//
#include <hip/hip_runtime.h>
#include <hip/hip_bf16.h>
#include <math.h>

#define BN 32
#define L 128
#define D 128
#define TT 127
#define NH 8

__device__ __forceinline__ float fast_gelu(float x) {
    float x2 = x * x;
    float y  = 0.7978845608f * x * fmaf(0.044715f, x2, 1.0f);
    float e  = __expf(2.0f * y);
    float t  = 1.0f - 2.0f * __builtin_amdgcn_rcpf(e + 1.0f);
    return 0.5f * x * (1.0f + t);
}

__device__ __forceinline__ float bfu_lo(unsigned u) { return __uint_as_float(u << 16); }
__device__ __forceinline__ float bfu_hi(unsigned u) { return __uint_as_float(u & 0xffff0000u); }
__device__ __forceinline__ unsigned short f2bf(float f) {
    unsigned u = __float_as_uint(f);
    return (unsigned short)((u + 0x7fffu + ((u >> 16) & 1u)) >> 16);
}

// ---------------- K1: QKV projection (+ weight prepack in block 0,0,0) ----------------
__global__ __launch_bounds__(256)
void qkv_kernel(const float* __restrict__ padded, const float* __restrict__ tok,
                const float* __restrict__ Wq, const float* __restrict__ bq,
                const float* __restrict__ Wk, const float* __restrict__ bk,
                const float* __restrict__ Wv, const float* __restrict__ bv,
                const float* __restrict__ Wb1, const float* __restrict__ bb1,
                const float* __restrict__ Wb2,
                const float* __restrict__ Wv1, const float* __restrict__ bv1,
                float* __restrict__ Qo, float* __restrict__ Ko, float* __restrict__ Vo,
                float* __restrict__ CW, float* __restrict__ RVW) {
    const int s = blockIdx.x;
    const int mat = blockIdx.y;
    const int chunk = blockIdx.z;
    const float* W = (mat == 0) ? Wq : (mat == 1) ? Wk : Wv;
    const float* bias = (mat == 0) ? bq : (mat == 1) ? bk : bv;
    float* outp = (mat == 0) ? Qo : (mat == 1) ? Ko : Vo;

    __shared__ float x_tile[32][D];
    const int tid = threadIdx.x;
    for (int idx = tid; idx < 32 * D; idx += 256) {
        int r = idx >> 7, c = idx & 127;
        int i = chunk * 32 + r;
        x_tile[r][c] = (i == 0) ? tok[c] : padded[(size_t)s * TT * D + (size_t)(i - 1) * D + c];
    }
    __syncthreads();

    const int c = tid & 127;
    const int rg = tid >> 7;
    const int r0 = rg * 16;
    float acc[16];
    const float bc = bias[c];
#pragma unroll
    for (int r = 0; r < 16; ++r) acc[r] = bc;
    for (int d = 0; d < D; ++d) {
        float wv = W[d * D + c];
#pragma unroll
        for (int r = 0; r < 16; ++r) acc[r] = fmaf(x_tile[r0 + r][d], wv, acc[r]);
    }
    size_t base = (size_t)s * L * D;
    for (int r = 0; r < 16; ++r)
        outp[base + (size_t)(chunk * 32 + r0 + r) * D + c] = acc[r];

    // ---- weight prepack (one block only) ----
    if (s == 0 && mat == 0 && chunk == 0) {
        if (tid < 64) {
            const int u = tid;
            CW[u * 16 + 0] = Wb1[0 * 64 + u];
            CW[u * 16 + 1] = Wb1[1 * 64 + u];
            CW[u * 16 + 2] = Wb1[2 * 64 + u];
            CW[u * 16 + 3] = Wb1[3 * 64 + u] + Wb1[4 * 64 + u];
            CW[u * 16 + 4] = Wb1[5 * 64 + u];
            CW[u * 16 + 5] = bb1[u];
            CW[u * 16 + 6] = 0.f;
            CW[u * 16 + 7] = 0.f;
#pragma unroll
            for (int k = 0; k < 8; ++k) CW[u * 16 + 8 + k] = Wb2[u * 8 + k];
        }
        if (tid < 128) {
            const int cc = tid;
            RVW[cc * 8 + 0] = Wv1[0 * 128 + cc];
            RVW[cc * 8 + 1] = Wv1[1 * 128 + cc];
            RVW[cc * 8 + 2] = Wv1[2 * 128 + cc];
            RVW[cc * 8 + 3] = Wv1[3 * 128 + cc] + Wv1[4 * 128 + cc];
            RVW[cc * 8 + 4] = Wv1[5 * 128 + cc];
            RVW[cc * 8 + 5] = bv1[cc];
            RVW[cc * 8 + 6] = 0.f;
            RVW[cc * 8 + 7] = 0.f;
        }
    }
}

// ---------------- K2: logits GEMM per (s,h). grid (BN, NH), block 256 ----------------
__global__ __launch_bounds__(256)
void logits_kernel(const float* __restrict__ Q, const float* __restrict__ K,
                   __hip_bfloat16* __restrict__ LW) {
    const int s = blockIdx.x;
    const int h = blockIdx.y;
    const int tid = threadIdx.x;

    __shared__ float Qs[128][16];
    __shared__ float Ks[128][16];
    for (int e = tid; e < 2048; e += 256) {
        int i = e >> 4, d = e & 15;
        Qs[i][d] = Q[((size_t)s * L + i) * D + h * 16 + d];
        Ks[i][d] = K[((size_t)s * L + i) * D + h * 16 + d];
    }
    __syncthreads();

    const int j = tid & 127;
    const int half = tid >> 7;
    float4 k0 = *(const float4*)&Ks[j][0];
    float4 k1 = *(const float4*)&Ks[j][4];
    float4 k2 = *(const float4*)&Ks[j][8];
    float4 k3 = *(const float4*)&Ks[j][12];

    __hip_bfloat16* lw = LW + ((size_t)(s * NH + h) * L) * L;
    for (int ii = 0; ii < 64; ++ii) {
        const int i = half * 64 + ii;
        float4 q0 = *(const float4*)&Qs[i][0];
        float4 q1 = *(const float4*)&Qs[i][4];
        float4 q2 = *(const float4*)&Qs[i][8];
        float4 q3 = *(const float4*)&Qs[i][12];
        float acc = q0.x * k0.x + q0.y * k0.y + q0.z * k0.z + q0.w * k0.w;
        acc = fmaf(q1.x, k1.x, acc); acc = fmaf(q1.y, k1.y, acc);
        acc = fmaf(q1.z, k1.z, acc); acc = fmaf(q1.w, k1.w, acc);
        acc = fmaf(q2.x, k2.x, acc); acc = fmaf(q2.y, k2.y, acc);
        acc = fmaf(q2.z, k2.z, acc); acc = fmaf(q2.w, k2.w, acc);
        acc = fmaf(q3.x, k3.x, acc); acc = fmaf(q3.y, k3.y, acc);
        acc = fmaf(q3.w, k3.w, acc); acc = fmaf(q3.z, k3.z, acc);
        lw[(size_t)i * L + j] = __float2bfloat16(acc * 0.25f);
    }
}

// ---------------- K3: core per (s,i). grid (L, BN), block 128 ----------------
__global__ __launch_bounds__(128, 4)
void attn_kernel(const float* __restrict__ padded, const int* __restrict__ masks,
                 const float* __restrict__ pos3d,
                 const float* __restrict__ gamma, const float* __restrict__ beta,
                 const float* __restrict__ tok,
                 const float* __restrict__ CW, const float* __restrict__ RVW,
                 const float* __restrict__ bb2, const float* __restrict__ bv2,
                 const float* __restrict__ V, const __hip_bfloat16* __restrict__ LW,
                 __hip_bfloat16* __restrict__ GS,
                 float* __restrict__ out) {
    const int i = blockIdx.x;
    const int s = blockIdx.y;
    const int tid = threadIdx.x;
    const int j = tid;
    const int wave = tid >> 6;

    __shared__ float4 feat4_lds[L];          // {dx,dy,dz,dist}
    __shared__ float  feat5_lds[L];          // dist2
    __shared__ float  w_lds[L][8];           // softmax weights [j][h]
    __shared__ unsigned short gs_part[4][NH][D];  // bf16 partial g-sums per jg
    __shared__ float  a1_part[D][4];         // partial V-sums per jg
    __shared__ float  reds[2][NH];

    // ---- early loads: logits + mask ----
    __hip_bfloat16 lr[NH];
#pragma unroll
    for (int hh = 0; hh < NH; ++hh)
        lr[hh] = LW[((size_t)(s * NH + hh) * L + i) * L + j];
    const int keep = (j == 0) ? 1 : masks[(size_t)s * TT + (j - 1)];

    // ---- relative features ----
    float pix = 0.f, piy = 0.f, piz = 0.f;
    if (i > 0) { const float* pp = pos3d + ((size_t)s * TT + (i - 1)) * 3; pix = pp[0]; piy = pp[1]; piz = pp[2]; }
    float pjx = 0.f, pjy = 0.f, pjz = 0.f;
    if (j > 0) { const float* pp = pos3d + ((size_t)s * TT + (j - 1)) * 3; pjx = pp[0]; pjy = pp[1]; pjz = pp[2]; }
    const float dx = pix - pjx, dy = piy - pjy, dz = piz - pjz;
    const float dist2 = dx * dx + dy * dy + dz * dz;
    const float dist = sqrtf(dist2);
    feat4_lds[j] = make_float4(dx, dy, dz, dist);
    feat5_lds[j] = dist2;

    // ---- rel-bias MLP: weights via wave-uniform (scalar) loads from CW ----
    float bias[NH];
#pragma unroll
    for (int hh = 0; hh < NH; ++hh) bias[hh] = 0.f;
    if (i > 0 && j > 0) {
        const float4* cw4 = (const float4*)CW;
#pragma unroll 2
        for (int u = 0; u < 64; ++u) {
            float4 wa  = cw4[u * 4 + 0];
            float4 wb  = cw4[u * 4 + 1];
            float4 w2a = cw4[u * 4 + 2];
            float4 w2b = cw4[u * 4 + 3];
            float hv = wb.y;
            hv = fmaf(dx, wa.x, hv);
            hv = fmaf(dy, wa.y, hv);
            hv = fmaf(dz, wa.z, hv);
            hv = fmaf(dist, wa.w, hv);
            hv = fmaf(dist2, wb.x, hv);
            hv = fast_gelu(hv);
            bias[0] = fmaf(hv, w2a.x, bias[0]);
            bias[1] = fmaf(hv, w2a.y, bias[1]);
            bias[2] = fmaf(hv, w2a.z, bias[2]);
            bias[3] = fmaf(hv, w2a.w, bias[3]);
            bias[4] = fmaf(hv, w2b.x, bias[4]);
            bias[5] = fmaf(hv, w2b.y, bias[5]);
            bias[6] = fmaf(hv, w2b.z, bias[6]);
            bias[7] = fmaf(hv, w2b.w, bias[7]);
        }
#pragma unroll
        for (int hh = 0; hh < NH; ++hh) bias[hh] += bb2[hh];
    }

    // ---- softmax (no max subtraction: logits ~O(1), masked -> exp(-3e38)=0) ----
    float p[NH];
#pragma unroll
    for (int hh = 0; hh < NH; ++hh) {
        float lv = __bfloat162float(lr[hh]) + bias[hh];
        if (!keep) lv = -3.0e38f;
        p[hh] = __expf(lv);
    }
#pragma unroll
    for (int hh = 0; hh < NH; ++hh) {
        float v = p[hh];
        for (int off = 32; off >= 1; off >>= 1) v += __shfl_xor(v, off, 64);
        if ((tid & 63) == 0) reds[wave][hh] = v;
    }
    __syncthreads();
#pragma unroll
    for (int hh = 0; hh < NH; ++hh) {
        float inv = __builtin_amdgcn_rcpf(reds[0][hh] + reds[1][hh]);
        p[hh] *= inv;
    }
    *(float4*)&w_lds[j][0] = make_float4(p[0], p[1], p[2], p[3]);
    *(float4*)&w_lds[j][4] = make_float4(p[4], p[5], p[6], p[7]);
    __syncthreads();   // feat + w ready

    // ---- pass 2: thread = (jg = tid>>5, channels c0..c0+3), 32 j's each ----
    const int jg = tid >> 5;
    const int cq = tid & 31;
    const int c0 = cq * 4;
    const int h0 = c0 >> 4;

    float rv[4][6];
#pragma unroll
    for (int k = 0; k < 4; ++k) {
        float4 ra = *(const float4*)&RVW[(size_t)(c0 + k) * 8 + 0];
        float4 rb = *(const float4*)&RVW[(size_t)(c0 + k) * 8 + 4];
        rv[k][0] = ra.x; rv[k][1] = ra.y; rv[k][2] = ra.z; rv[k][3] = ra.w;
        rv[k][4] = rb.x; rv[k][5] = rb.y;
    }

    float gs[NH][4];
#pragma unroll
    for (int hh = 0; hh < NH; ++hh)
#pragma unroll
        for (int k = 0; k < 4; ++k) gs[hh][k] = 0.f;
    float a1[4] = {0.f, 0.f, 0.f, 0.f};

    const float* Vs = V + (size_t)s * L * D;
    float4 vbuf = *(const float4*)&Vs[(size_t)(jg * 32) * D + c0];

#pragma unroll 4
    for (int r = 0; r < 32; ++r) {
        const int jt = jg * 32 + r;
        float4 vcur = vbuf;
        if (r < 31) vbuf = *(const float4*)&Vs[(size_t)(jt + 1) * D + c0];
        float4 fa = feat4_lds[jt];
        float f5 = feat5_lds[jt];
        float wown = w_lds[jt][h0];
        a1[0] = fmaf(wown, vcur.x, a1[0]);
        a1[1] = fmaf(wown, vcur.y, a1[1]);
        a1[2] = fmaf(wown, vcur.z, a1[2]);
        a1[3] = fmaf(wown, vcur.w, a1[3]);
        if (i > 0 && jt > 0) {
            float4 wlo = *(const float4*)&w_lds[jt][0];
            float4 whi = *(const float4*)&w_lds[jt][4];
            float g[4];
#pragma unroll
            for (int k = 0; k < 4; ++k) {
                float hv = rv[k][5];
                hv = fmaf(fa.x, rv[k][0], hv);
                hv = fmaf(fa.y, rv[k][1], hv);
                hv = fmaf(fa.z, rv[k][2], hv);
                hv = fmaf(fa.w, rv[k][3], hv);
                hv = fmaf(f5,  rv[k][4], hv);
                g[k] = fast_gelu(hv);
            }
#pragma unroll
            for (int k = 0; k < 4; ++k) {
                gs[0][k] = fmaf(wlo.x, g[k], gs[0][k]);
                gs[1][k] = fmaf(wlo.y, g[k], gs[1][k]);
                gs[2][k] = fmaf(wlo.z, g[k], gs[2][k]);
                gs[3][k] = fmaf(wlo.w, g[k], gs[3][k]);
                gs[4][k] = fmaf(whi.x, g[k], gs[4][k]);
                gs[5][k] = fmaf(whi.y, g[k], gs[5][k]);
                gs[6][k] = fmaf(whi.z, g[k], gs[6][k]);
                gs[7][k] = fmaf(whi.w, g[k], gs[7][k]);
            }
        }
    }

    if (i > 0) {
#pragma unroll
        for (int hh = 0; hh < NH; ++hh) {
            unsigned lo = (unsigned)f2bf(gs[hh][0]) | ((unsigned)f2bf(gs[hh][1]) << 16);
            unsigned hi = (unsigned)f2bf(gs[hh][2]) | ((unsigned)f2bf(gs[hh][3]) << 16);
            *(uint2*)&gs_part[jg][hh][c0] = make_uint2(lo, hi);
        }
    }
#pragma unroll
    for (int k = 0; k < 4; ++k) a1_part[c0 + k][jg] = a1[k];
    __syncthreads();

    // ---- reduction across the 4 jg groups ----
    float a1f;
    {
        float4 ap = *(const float4*)&a1_part[tid][0];
        a1f = (ap.x + ap.y) + (ap.z + ap.w);
    }

    if (i > 0) {
        const int rh = tid >> 4;
        const int rm = tid & 15;
        float acc[8];
#pragma unroll
        for (int k = 0; k < 8; ++k) acc[k] = 0.f;
#pragma unroll
        for (int g4 = 0; g4 < 4; ++g4) {
            uint4 raw = *(const uint4*)&gs_part[g4][rh][rm * 8];
            acc[0] += bfu_lo(raw.x); acc[1] += bfu_hi(raw.x);
            acc[2] += bfu_lo(raw.y); acc[3] += bfu_hi(raw.y);
            acc[4] += bfu_lo(raw.z); acc[5] += bfu_hi(raw.z);
            acc[6] += bfu_lo(raw.w); acc[7] += bfu_hi(raw.w);
        }
        uint4 ow;
        ow.x = (unsigned)f2bf(acc[0]) | ((unsigned)f2bf(acc[1]) << 16);
        ow.y = (unsigned)f2bf(acc[2]) | ((unsigned)f2bf(acc[3]) << 16);
        ow.z = (unsigned)f2bf(acc[4]) | ((unsigned)f2bf(acc[5]) << 16);
        ow.w = (unsigned)f2bf(acc[6]) | ((unsigned)f2bf(acc[7]) << 16);
        *(uint4*)&GS[((size_t)(s * L + i) * NH + rh) * D + rm * 8] = ow;

        const float S1 = 1.0f - w_lds[0][tid >> 4];
        const size_t o = (size_t)s * TT * D + (size_t)(i - 1) * D + tid;
        out[o] = a1f + S1 * bv2[tid] + padded[o];
    } else {
        __shared__ float red2[2][2];
        float st = a1f + tok[tid];
        float sum = st, sum2 = st * st;
        for (int off = 32; off >= 1; off >>= 1) {
            sum += __shfl_xor(sum, off, 64);
            sum2 += __shfl_xor(sum2, off, 64);
        }
        if ((tid & 63) == 0) { red2[wave][0] = sum; red2[wave][1] = sum2; }
        __syncthreads();
        sum = red2[0][0] + red2[1][0];
        sum2 = red2[0][1] + red2[1][1];
        const float mu = sum * (1.0f / 128.0f);
        const float var = sum2 * (1.0f / 128.0f) - mu * mu;
        const float y = (st - mu) * rsqrtf(var + 1e-5f) * gamma[tid] + beta[tid];
        out[(size_t)BN * TT * D + (size_t)s * D + tid] = y;
    }
}

// ---------------- K4: a2 = gs @ Wv2, added into out. grid (BN, NH), block 256 ----------------
__global__ __launch_bounds__(256)
void a2_kernel(const __hip_bfloat16* __restrict__ GS, const float* __restrict__ Wv2,
               float* __restrict__ out) {
    const int s = blockIdx.x;
    const int h = blockIdx.y;
    const int tid = threadIdx.x;

    __shared__ unsigned short gss[128][136];
    __shared__ float wv2s[128][17];

    for (int e = tid; e < 4096; e += 256) {
        int i = e >> 5, c4 = (e & 31) * 4;
        uint2 raw = make_uint2(0u, 0u);
        if (i > 0) raw = *(const uint2*)&GS[((size_t)(s * L + i) * NH + h) * D + c4];
        *(uint2*)&gss[i][c4] = raw;
    }
    for (int e = tid; e < 2048; e += 256) {
        int c = e >> 4, w = e & 15;
        wv2s[c][w] = Wv2[(size_t)c * D + h * 16 + w];
    }
    __syncthreads();

    const int cc = tid & 15;
    const int ig = tid >> 4;
    float acc[8];
#pragma unroll
    for (int r = 0; r < 8; ++r) acc[r] = 0.f;

    for (int c = 0; c < 128; c += 8) {
        float wv[8];
#pragma unroll
        for (int k = 0; k < 8; ++k) wv[k] = wv2s[c + k][cc];
#pragma unroll
        for (int r = 0; r < 8; ++r) {
            const int i = ig + 16 * r;
            uint4 raw = *(const uint4*)&gss[i][c];
            acc[r] = fmaf(bfu_lo(raw.x), wv[0], acc[r]);
            acc[r] = fmaf(bfu_hi(raw.x), wv[1], acc[r]);
            acc[r] = fmaf(bfu_lo(raw.y), wv[2], acc[r]);
            acc[r] = fmaf(bfu_hi(raw.y), wv[3], acc[r]);
            acc[r] = fmaf(bfu_lo(raw.z), wv[4], acc[r]);
            acc[r] = fmaf(bfu_hi(raw.z), wv[5], acc[r]);
            acc[r] = fmaf(bfu_lo(raw.w), wv[6], acc[r]);
            acc[r] = fmaf(bfu_hi(raw.w), wv[7], acc[r]);
        }
    }

#pragma unroll
    for (int r = 0; r < 8; ++r) {
        const int i = ig + 16 * r;
        if (i > 0) {
            const size_t o = (size_t)s * TT * D + (size_t)(i - 1) * D + h * 16 + cc;
            out[o] += acc[r];
        }
    }
}

extern "C" void kernel_launch(void* const* d_in, const int* in_sizes, int n_in,
                              void* d_out, int out_size, void* d_ws, size_t ws_size,
                              hipStream_t stream) {
    const float* padded = (const float*)d_in[0];
    const int*   masks  = (const int*)d_in[1];
    const float* pos3d  = (const float*)d_in[2];
    const float* Wq = (const float*)d_in[3];
    const float* bq = (const float*)d_in[4];
    const float* Wk = (const float*)d_in[5];
    const float* bk = (const float*)d_in[6];
    const float* Wv = (const float*)d_in[7];
    const float* bv = (const float*)d_in[8];
    const float* gamma = (const float*)d_in[9];
    const float* beta  = (const float*)d_in[10];
    const float* tok   = (const float*)d_in[11];
    const float* Wb1 = (const float*)d_in[12];
    const float* bb1 = (const float*)d_in[13];
    const float* Wb2 = (const float*)d_in[14];
    const float* bb2 = (const float*)d_in[15];
    const float* Wv1 = (const float*)d_in[16];
    const float* bv1 = (const float*)d_in[17];
    const float* Wv2 = (const float*)d_in[18];
    const float* bv2 = (const float*)d_in[19];
    float* out = (float*)d_out;

    float* Q  = (float*)d_ws;
    float* K  = Q + (size_t)BN * L * D;
    float* Vw = K + (size_t)BN * L * D;
    __hip_bfloat16* LW = (__hip_bfloat16*)(Vw + (size_t)BN * L * D);
    __hip_bfloat16* GS = LW + (size_t)BN * NH * L * L;
    float* CW  = (float*)(GS + (size_t)BN * L * NH * D);
    float* RVW = CW + 64 * 16;

    qkv_kernel<<<dim3(BN, 3, 4), 256, 0, stream>>>(padded, tok, Wq, bq, Wk, bk, Wv, bv,
                                                   Wb1, bb1, Wb2, Wv1, bv1,
                                                   Q, K, Vw, CW, RVW);
    logits_kernel<<<dim3(BN, NH), 256, 0, stream>>>(Q, K, LW);
    attn_kernel<<<dim3(L, BN), 128, 0, stream>>>(padded, masks, pos3d, gamma, beta, tok,
                                                 CW, RVW, bb2, bv2,
                                                 Vw, LW, GS, out);
    a2_kernel<<<dim3(BN, NH), 256, 0, stream>>>(GS, Wv2, out);
}

// Round 6
// 103.468 us; speedup vs baseline: 1.1938x; 1.1938x over previous
//
#include <hip/hip_runtime.h>
#include <hip/hip_bf16.h>
#include <math.h>

#define BN 32
#define L 128
#define D 128
#define TT 127
#define NH 8

typedef float f32x4 __attribute__((ext_vector_type(4)));
typedef short s16x8 __attribute__((ext_vector_type(8)));

__device__ __forceinline__ float gelu_sig(float x) {
    // x * sigmoid(1.702x); |err vs erf-gelu| <= ~0.021 -> ~3e-3 at outputs
    float e = __expf(-1.702f * x);
    return x * __builtin_amdgcn_rcpf(1.0f + e);
}
__device__ __forceinline__ unsigned short f2bf(float f) {
    unsigned u = __float_as_uint(f);
    return (unsigned short)((u + 0x7fffu + ((u >> 16) & 1u)) >> 16);
}

// ---------------- K1: QKV projection (+ weight prepack in block 0,0,0) ----------------
__global__ __launch_bounds__(256)
void qkv_kernel(const float* __restrict__ padded, const float* __restrict__ tok,
                const float* __restrict__ Wq, const float* __restrict__ bq,
                const float* __restrict__ Wk, const float* __restrict__ bk,
                const float* __restrict__ Wv, const float* __restrict__ bv,
                const float* __restrict__ Wb1, const float* __restrict__ bb1,
                const float* __restrict__ Wb2,
                const float* __restrict__ Wv1, const float* __restrict__ bv1,
                const float* __restrict__ Wv2,
                float* __restrict__ Qo, float* __restrict__ Ko, float* __restrict__ Vo,
                float* __restrict__ CW, float* __restrict__ RVW,
                unsigned short* __restrict__ WV2F) {
    const int s = blockIdx.x;
    const int mat = blockIdx.y;
    const int chunk = blockIdx.z;
    const float* W = (mat == 0) ? Wq : (mat == 1) ? Wk : Wv;
    const float* bias = (mat == 0) ? bq : (mat == 1) ? bk : bv;
    float* outp = (mat == 0) ? Qo : (mat == 1) ? Ko : Vo;

    __shared__ float x_tile[32][D];
    const int tid = threadIdx.x;
    for (int idx = tid; idx < 32 * D; idx += 256) {
        int r = idx >> 7, c = idx & 127;
        int i = chunk * 32 + r;
        x_tile[r][c] = (i == 0) ? tok[c] : padded[(size_t)s * TT * D + (size_t)(i - 1) * D + c];
    }
    __syncthreads();

    const int c = tid & 127;
    const int rg = tid >> 7;
    const int r0 = rg * 16;
    float acc[16];
    const float bc = bias[c];
#pragma unroll
    for (int r = 0; r < 16; ++r) acc[r] = bc;
    for (int d = 0; d < D; ++d) {
        float wv = W[d * D + c];
#pragma unroll
        for (int r = 0; r < 16; ++r) acc[r] = fmaf(x_tile[r0 + r][d], wv, acc[r]);
    }
    size_t base = (size_t)s * L * D;
    for (int r = 0; r < 16; ++r)
        outp[base + (size_t)(chunk * 32 + r0 + r) * D + c] = acc[r];

    // ---- weight prepack (one block only; stream-serialized before K2/K3) ----
    if (s == 0 && mat == 0 && chunk == 0) {
        if (tid < 64) {
            const int u = tid;
            CW[u * 16 + 0] = Wb1[0 * 64 + u];
            CW[u * 16 + 1] = Wb1[1 * 64 + u];
            CW[u * 16 + 2] = Wb1[2 * 64 + u];
            CW[u * 16 + 3] = Wb1[3 * 64 + u] + Wb1[4 * 64 + u];
            CW[u * 16 + 4] = Wb1[5 * 64 + u];
            CW[u * 16 + 5] = bb1[u];
            CW[u * 16 + 6] = 0.f;
            CW[u * 16 + 7] = 0.f;
#pragma unroll
            for (int k = 0; k < 8; ++k) CW[u * 16 + 8 + k] = Wb2[u * 8 + k];
        }
        if (tid < 128) {
            const int cc = tid;
            RVW[cc * 8 + 0] = Wv1[0 * 128 + cc];
            RVW[cc * 8 + 1] = Wv1[1 * 128 + cc];
            RVW[cc * 8 + 2] = Wv1[2 * 128 + cc];
            RVW[cc * 8 + 3] = Wv1[3 * 128 + cc] + Wv1[4 * 128 + cc];
            RVW[cc * 8 + 4] = Wv1[5 * 128 + cc];
            RVW[cc * 8 + 5] = bv1[cc];
            RVW[cc * 8 + 6] = 0.f;
            RVW[cc * 8 + 7] = 0.f;
        }
        // Wv2 -> B-fragment order for mfma_f32_16x16x32_bf16:
        // frag f = kt*8+ng; element (lane, e) = Wv2[kt*32+(lane>>4)*8+e][ng*16+(lane&15)]
        for (int idx = tid; idx < 16384; idx += 256) {
            int f = idx >> 9, r = idx & 511, ln = r >> 3, e = r & 7;
            int kt = f >> 3, ng = f & 7;
            int row = kt * 32 + (ln >> 4) * 8 + e;
            int col = ng * 16 + (ln & 15);
            WV2F[idx] = f2bf(Wv2[(size_t)row * D + col]);
        }
    }
}

// ---------------- K2: logits GEMM per (s,h). grid (BN, NH), block 256 ----------------
__global__ __launch_bounds__(256)
void logits_kernel(const float* __restrict__ Q, const float* __restrict__ K,
                   __hip_bfloat16* __restrict__ LW) {
    const int s = blockIdx.x;
    const int h = blockIdx.y;
    const int tid = threadIdx.x;

    __shared__ float Qs[128][16];
    __shared__ float Ks[128][16];
    for (int e = tid; e < 2048; e += 256) {
        int i = e >> 4, d = e & 15;
        Qs[i][d] = Q[((size_t)s * L + i) * D + h * 16 + d];
        Ks[i][d] = K[((size_t)s * L + i) * D + h * 16 + d];
    }
    __syncthreads();

    const int j = tid & 127;
    const int half = tid >> 7;
    float4 k0 = *(const float4*)&Ks[j][0];
    float4 k1 = *(const float4*)&Ks[j][4];
    float4 k2 = *(const float4*)&Ks[j][8];
    float4 k3 = *(const float4*)&Ks[j][12];

    __hip_bfloat16* lw = LW + ((size_t)(s * NH + h) * L) * L;
    for (int ii = 0; ii < 64; ++ii) {
        const int i = half * 64 + ii;
        float4 q0 = *(const float4*)&Qs[i][0];
        float4 q1 = *(const float4*)&Qs[i][4];
        float4 q2 = *(const float4*)&Qs[i][8];
        float4 q3 = *(const float4*)&Qs[i][12];
        float acc = q0.x * k0.x + q0.y * k0.y + q0.z * k0.z + q0.w * k0.w;
        acc = fmaf(q1.x, k1.x, acc); acc = fmaf(q1.y, k1.y, acc);
        acc = fmaf(q1.z, k1.z, acc); acc = fmaf(q1.w, k1.w, acc);
        acc = fmaf(q2.x, k2.x, acc); acc = fmaf(q2.y, k2.y, acc);
        acc = fmaf(q2.z, k2.z, acc); acc = fmaf(q2.w, k2.w, acc);
        acc = fmaf(q3.x, k3.x, acc); acc = fmaf(q3.y, k3.y, acc);
        acc = fmaf(q3.w, k3.w, acc); acc = fmaf(q3.z, k3.z, acc);
        lw[(size_t)i * L + j] = __float2bfloat16(acc * 0.25f);
    }
}

// ---------------- K3: core per (s,i). grid (L, BN), block 128 (2 waves) ----------------
__global__ __launch_bounds__(128, 3)
void attn_kernel(const float* __restrict__ padded, const int* __restrict__ masks,
                 const float* __restrict__ pos3d,
                 const float* __restrict__ gamma, const float* __restrict__ beta,
                 const float* __restrict__ tok,
                 const float* __restrict__ CW, const float* __restrict__ RVW,
                 const unsigned short* __restrict__ WV2F,
                 const float* __restrict__ bb2, const float* __restrict__ bv2,
                 const float* __restrict__ V, const __hip_bfloat16* __restrict__ LW,
                 float* __restrict__ out) {
    const int i = blockIdx.x;
    const int s = blockIdx.y;
    const int tid = threadIdx.x;
    const int wave = tid >> 6;       // 0/1: owns c-range [wave*64, wave*64+64)
    const int lane = tid & 63;
    const int hA = lane & 15;        // mfma A-row / D-col index
    const int kg = lane >> 4;        // mfma k-group

    __shared__ float4 feat4_lds[144];      // idx j + (j>>3): {dx,dy,dz,dist}
    __shared__ float  feat5_lds[L];        // dist2
    __shared__ float  w_lds[NH][132];      // softmax weights [h][j]
    __shared__ float  gs_lds[NH][132];     // GS rows (f32)
    __shared__ float  a1_part[4][132];
    __shared__ float  a2_lds[D];
    __shared__ float  reds[2][NH];
    __shared__ float  red2[2][2];

    // ---- early loads: logits + mask ----
    __hip_bfloat16 lr[NH];
#pragma unroll
    for (int hh = 0; hh < NH; ++hh)
        lr[hh] = LW[((size_t)(s * NH + hh) * L + i) * L + tid];
    const int keep = (tid == 0) ? 1 : masks[(size_t)s * TT + (tid - 1)];

    // ---- relative features for pair (i, j=tid) ----
    float pix = 0.f, piy = 0.f, piz = 0.f;
    if (i > 0) { const float* pp = pos3d + ((size_t)s * TT + (i - 1)) * 3; pix = pp[0]; piy = pp[1]; piz = pp[2]; }
    float pjx = 0.f, pjy = 0.f, pjz = 0.f;
    if (tid > 0) { const float* pp = pos3d + ((size_t)s * TT + (tid - 1)) * 3; pjx = pp[0]; pjy = pp[1]; pjz = pp[2]; }
    const float dx = pix - pjx, dy = piy - pjy, dz = piz - pjz;
    const float dist2 = dx * dx + dy * dy + dz * dz;
    const float dist = sqrtf(dist2);
    feat4_lds[tid + (tid >> 3)] = make_float4(dx, dy, dz, dist);
    feat5_lds[tid] = dist2;

    __syncthreads();

    // ---- rel-bias MLP (wave-uniform scalar loads from CW) ----
    float bias[NH];
#pragma unroll
    for (int hh = 0; hh < NH; ++hh) bias[hh] = 0.f;
    if (i > 0 && tid > 0) {
        const float4* cw4 = (const float4*)CW;
#pragma unroll 2
        for (int u = 0; u < 64; ++u) {
            float4 wa  = cw4[u * 4 + 0];
            float4 wb  = cw4[u * 4 + 1];
            float4 w2a = cw4[u * 4 + 2];
            float4 w2b = cw4[u * 4 + 3];
            float hv = wb.y;
            hv = fmaf(dx, wa.x, hv);
            hv = fmaf(dy, wa.y, hv);
            hv = fmaf(dz, wa.z, hv);
            hv = fmaf(dist, wa.w, hv);
            hv = fmaf(dist2, wb.x, hv);
            hv = gelu_sig(hv);
            bias[0] = fmaf(hv, w2a.x, bias[0]);
            bias[1] = fmaf(hv, w2a.y, bias[1]);
            bias[2] = fmaf(hv, w2a.z, bias[2]);
            bias[3] = fmaf(hv, w2a.w, bias[3]);
            bias[4] = fmaf(hv, w2b.x, bias[4]);
            bias[5] = fmaf(hv, w2b.y, bias[5]);
            bias[6] = fmaf(hv, w2b.z, bias[6]);
            bias[7] = fmaf(hv, w2b.w, bias[7]);
        }
#pragma unroll
        for (int hh = 0; hh < NH; ++hh) bias[hh] += bb2[hh];
    }

    // ---- softmax (no max subtraction; masked -> exp(-3e38)=0) ----
    float p[NH];
#pragma unroll
    for (int hh = 0; hh < NH; ++hh) {
        float lv = __bfloat162float(lr[hh]) + bias[hh];
        if (!keep) lv = -3.0e38f;
        p[hh] = __expf(lv);
    }
#pragma unroll
    for (int hh = 0; hh < NH; ++hh) {
        float v = p[hh];
        for (int off = 32; off >= 1; off >>= 1) v += __shfl_xor(v, off, 64);
        if (lane == 0) reds[wave][hh] = v;
    }
    __syncthreads();
#pragma unroll
    for (int hh = 0; hh < NH; ++hh) {
        float inv = __builtin_amdgcn_rcpf(reds[0][hh] + reds[1][hh]);
        w_lds[hh][tid] = p[hh] * inv;
    }
    __syncthreads();   // w + feat ready

    // ---- a1 setup (VALU path): thread = (jg, 4 consecutive channels) ----
    const int jg = tid >> 5;
    const int c0v = (tid & 31) * 4;
    const int h0v = c0v >> 4;
    const float* Vs = V + (size_t)s * L * D;

    if (i > 0) {
        // ---- A-fragments of W (rows h<8, zero row pad; j=0 column zeroed) ----
        s16x8 wfrag[4];
#pragma unroll
        for (int kt = 0; kt < 4; ++kt) {
            s16x8 wf;
#pragma unroll
            for (int e = 0; e < 8; ++e) wf[e] = 0;
            if (hA < NH) {
                const int j0 = kt * 32 + kg * 8;
                float4 wv0 = *(const float4*)&w_lds[hA][j0];
                float4 wv1 = *(const float4*)&w_lds[hA][j0 + 4];
                if (kt == 0 && kg == 0) wv0.x = 0.f;   // exclude j==0 from g-sum
                wf[0] = (short)f2bf(wv0.x); wf[1] = (short)f2bf(wv0.y);
                wf[2] = (short)f2bf(wv0.z); wf[3] = (short)f2bf(wv0.w);
                wf[4] = (short)f2bf(wv1.x); wf[5] = (short)f2bf(wv1.y);
                wf[6] = (short)f2bf(wv1.z); wf[7] = (short)f2bf(wv1.w);
            }
            wfrag[kt] = wf;
        }

        // per-lane rel-val weights for its 4 fragment columns c = wave*64+n*16+hA
        float rvw[4][6];
#pragma unroll
        for (int n = 0; n < 4; ++n) {
            const int c = wave * 64 + n * 16 + hA;
            float4 ra = *(const float4*)&RVW[(size_t)c * 8 + 0];
            rvw[n][0] = ra.x; rvw[n][1] = ra.y; rvw[n][2] = ra.z; rvw[n][3] = ra.w;
            rvw[n][4] = RVW[(size_t)c * 8 + 4];
            rvw[n][5] = RVW[(size_t)c * 8 + 5];
        }

        f32x4 accG[4];
#pragma unroll
        for (int n = 0; n < 4; ++n) accG[n] = (f32x4){0.f, 0.f, 0.f, 0.f};

        // ---- G computed directly in B-fragment layout; GS via MFMA ----
#pragma unroll
        for (int kt = 0; kt < 4; ++kt) {
            const int jb = kt * 32 + kg * 8;
            s16x8 bfr[4];
#pragma unroll
            for (int e = 0; e < 8; ++e) {
                const int j = jb + e;
                float4 fa = feat4_lds[j + (j >> 3)];
                float f5 = feat5_lds[j];
#pragma unroll
                for (int n = 0; n < 4; ++n) {
                    float hv = rvw[n][5];
                    hv = fmaf(fa.x, rvw[n][0], hv);
                    hv = fmaf(fa.y, rvw[n][1], hv);
                    hv = fmaf(fa.z, rvw[n][2], hv);
                    hv = fmaf(fa.w, rvw[n][3], hv);
                    hv = fmaf(f5,  rvw[n][4], hv);
                    bfr[n][e] = (short)f2bf(gelu_sig(hv));
                }
            }
#pragma unroll
            for (int n = 0; n < 4; ++n)
                accG[n] = __builtin_amdgcn_mfma_f32_16x16x32_bf16(wfrag[kt], bfr[n], accG[n], 0, 0, 0);
        }

        // ---- a1 (VALU) overlaps MFMA completion ----
        float a1a[4] = {0.f, 0.f, 0.f, 0.f};
        float4 vbuf = *(const float4*)&Vs[(size_t)(jg * 32) * D + c0v];
#pragma unroll 4
        for (int r = 0; r < 32; ++r) {
            const int jt = jg * 32 + r;
            float4 vcur = vbuf;
            if (r < 31) vbuf = *(const float4*)&Vs[(size_t)(jt + 1) * D + c0v];
            const float wj = w_lds[h0v][jt];
            a1a[0] = fmaf(wj, vcur.x, a1a[0]);
            a1a[1] = fmaf(wj, vcur.y, a1a[1]);
            a1a[2] = fmaf(wj, vcur.z, a1a[2]);
            a1a[3] = fmaf(wj, vcur.w, a1a[3]);
        }
        *(float4*)&a1_part[jg][c0v] = make_float4(a1a[0], a1a[1], a1a[2], a1a[3]);

        // GS rows 0..7 live in lanes 0..31 (D-layout row=(lane>>4)*4+reg)
        if (lane < 32) {
#pragma unroll
            for (int n = 0; n < 4; ++n)
#pragma unroll
                for (int r = 0; r < 4; ++r)
                    gs_lds[(lane >> 4) * 4 + r][wave * 64 + n * 16 + hA] = accG[n][r];
        }
        __syncthreads();

        // ---- a2 = GS @ Wv2 via MFMA (B prepacked in WV2F) ----
        f32x4 acc2[4];
#pragma unroll
        for (int n = 0; n < 4; ++n) acc2[n] = (f32x4){0.f, 0.f, 0.f, 0.f};
#pragma unroll
        for (int kt = 0; kt < 4; ++kt) {
            s16x8 gf;
#pragma unroll
            for (int e = 0; e < 8; ++e) gf[e] = 0;
            if (hA < NH) {
                const int k0 = kt * 32 + kg * 8;
                float4 g0 = *(const float4*)&gs_lds[hA][k0];
                float4 g1 = *(const float4*)&gs_lds[hA][k0 + 4];
                gf[0] = (short)f2bf(g0.x); gf[1] = (short)f2bf(g0.y);
                gf[2] = (short)f2bf(g0.z); gf[3] = (short)f2bf(g0.w);
                gf[4] = (short)f2bf(g1.x); gf[5] = (short)f2bf(g1.y);
                gf[6] = (short)f2bf(g1.z); gf[7] = (short)f2bf(g1.w);
            }
#pragma unroll
            for (int n = 0; n < 4; ++n) {
                const int f = kt * 8 + wave * 4 + n;
                s16x8 bw = *(const s16x8*)&WV2F[((size_t)f * 64 + lane) * 8];
                acc2[n] = __builtin_amdgcn_mfma_f32_16x16x32_bf16(gf, bw, acc2[n], 0, 0, 0);
            }
        }
        // diagonal-head extraction: row hh=wave*4+n lives in lane-group 'wave', reg n
#pragma unroll
        for (int n = 0; n < 4; ++n)
            if (kg == wave) a2_lds[wave * 64 + n * 16 + hA] = acc2[n][n];
        __syncthreads();

        // ---- epilogue ----
        const float a1f = a1_part[0][tid] + a1_part[1][tid] + a1_part[2][tid] + a1_part[3][tid];
        const float S1 = 1.0f - w_lds[tid >> 4][0];
        const size_t o = (size_t)s * TT * D + (size_t)(i - 1) * D + tid;
        out[o] = a1f + a2_lds[tid] + S1 * bv2[tid] + padded[o];
    } else {
        // ---- cls row: a2 == 0; V-reduce + layernorm ----
        float a1a[4] = {0.f, 0.f, 0.f, 0.f};
        float4 vbuf = *(const float4*)&Vs[(size_t)(jg * 32) * D + c0v];
#pragma unroll 4
        for (int r = 0; r < 32; ++r) {
            const int jt = jg * 32 + r;
            float4 vcur = vbuf;
            if (r < 31) vbuf = *(const float4*)&Vs[(size_t)(jt + 1) * D + c0v];
            const float wj = w_lds[h0v][jt];
            a1a[0] = fmaf(wj, vcur.x, a1a[0]);
            a1a[1] = fmaf(wj, vcur.y, a1a[1]);
            a1a[2] = fmaf(wj, vcur.z, a1a[2]);
            a1a[3] = fmaf(wj, vcur.w, a1a[3]);
        }
        *(float4*)&a1_part[jg][c0v] = make_float4(a1a[0], a1a[1], a1a[2], a1a[3]);
        __syncthreads();
        const float a1f = a1_part[0][tid] + a1_part[1][tid] + a1_part[2][tid] + a1_part[3][tid];

        float st = a1f + tok[tid];
        float sum = st, sum2 = st * st;
        for (int off = 32; off >= 1; off >>= 1) {
            sum += __shfl_xor(sum, off, 64);
            sum2 += __shfl_xor(sum2, off, 64);
        }
        if (lane == 0) { red2[wave][0] = sum; red2[wave][1] = sum2; }
        __syncthreads();
        sum = red2[0][0] + red2[1][0];
        sum2 = red2[0][1] + red2[1][1];
        const float mu = sum * (1.0f / 128.0f);
        const float var = sum2 * (1.0f / 128.0f) - mu * mu;
        const float y = (st - mu) * rsqrtf(var + 1e-5f) * gamma[tid] + beta[tid];
        out[(size_t)BN * TT * D + (size_t)s * D + tid] = y;
    }
}

extern "C" void kernel_launch(void* const* d_in, const int* in_sizes, int n_in,
                              void* d_out, int out_size, void* d_ws, size_t ws_size,
                              hipStream_t stream) {
    const float* padded = (const float*)d_in[0];
    const int*   masks  = (const int*)d_in[1];
    const float* pos3d  = (const float*)d_in[2];
    const float* Wq = (const float*)d_in[3];
    const float* bq = (const float*)d_in[4];
    const float* Wk = (const float*)d_in[5];
    const float* bk = (const float*)d_in[6];
    const float* Wv = (const float*)d_in[7];
    const float* bv = (const float*)d_in[8];
    const float* gamma = (const float*)d_in[9];
    const float* beta  = (const float*)d_in[10];
    const float* tok   = (const float*)d_in[11];
    const float* Wb1 = (const float*)d_in[12];
    const float* bb1 = (const float*)d_in[13];
    const float* Wb2 = (const float*)d_in[14];
    const float* bb2 = (const float*)d_in[15];
    const float* Wv1 = (const float*)d_in[16];
    const float* bv1 = (const float*)d_in[17];
    const float* Wv2 = (const float*)d_in[18];
    const float* bv2 = (const float*)d_in[19];
    float* out = (float*)d_out;

    float* Q  = (float*)d_ws;
    float* K  = Q + (size_t)BN * L * D;
    float* Vw = K + (size_t)BN * L * D;
    __hip_bfloat16* LW = (__hip_bfloat16*)(Vw + (size_t)BN * L * D);
    float* CW  = (float*)(LW + (size_t)BN * NH * L * L);
    float* RVW = CW + 64 * 16;
    unsigned short* WV2F = (unsigned short*)(RVW + 128 * 8);

    qkv_kernel<<<dim3(BN, 3, 4), 256, 0, stream>>>(padded, tok, Wq, bq, Wk, bk, Wv, bv,
                                                   Wb1, bb1, Wb2, Wv1, bv1, Wv2,
                                                   Q, K, Vw, CW, RVW, WV2F);
    logits_kernel<<<dim3(BN, NH), 256, 0, stream>>>(Q, K, LW);
    attn_kernel<<<dim3(L, BN), 128, 0, stream>>>(padded, masks, pos3d, gamma, beta, tok,
                                                 CW, RVW, WV2F, bb2, bv2,
                                                 Vw, LW, out);
}

// Round 7
// 89.390 us; speedup vs baseline: 1.3818x; 1.1575x over previous
//
#include <hip/hip_runtime.h>
#include <hip/hip_bf16.h>
#include <math.h>

#define BN 32
#define L 128
#define D 128
#define TT 127
#define NH 8

typedef float f32x4 __attribute__((ext_vector_type(4)));
typedef short s16x8 __attribute__((ext_vector_type(8)));

__device__ __forceinline__ float gelu_sig(float x) {
    // x * sigmoid(1.702x); |err vs erf-gelu| <= ~0.021 -> ~3e-3 at outputs
    float e = __expf(-1.702f * x);
    return x * __builtin_amdgcn_rcpf(1.0f + e);
}
__device__ __forceinline__ unsigned short f2bf(float f) {
    unsigned u = __float_as_uint(f);
    return (unsigned short)((u + 0x7fffu + ((u >> 16) & 1u)) >> 16);
}

// ---------------- K1: QKV projection (+ weight prepack in block 0,0,0) ----------------
__global__ __launch_bounds__(256)
void qkv_kernel(const float* __restrict__ padded, const float* __restrict__ tok,
                const float* __restrict__ Wq, const float* __restrict__ bq,
                const float* __restrict__ Wk, const float* __restrict__ bk,
                const float* __restrict__ Wv, const float* __restrict__ bv,
                const float* __restrict__ Wb1, const float* __restrict__ bb1,
                const float* __restrict__ Wb2,
                const float* __restrict__ Wv1, const float* __restrict__ bv1,
                const float* __restrict__ Wv2,
                float* __restrict__ Qo, float* __restrict__ Ko, float* __restrict__ Vo,
                float* __restrict__ CW, float* __restrict__ RVW,
                unsigned short* __restrict__ WV2F) {
    const int s = blockIdx.x;
    const int mat = blockIdx.y;
    const int chunk = blockIdx.z;
    const float* W = (mat == 0) ? Wq : (mat == 1) ? Wk : Wv;
    const float* bias = (mat == 0) ? bq : (mat == 1) ? bk : bv;
    float* outp = (mat == 0) ? Qo : (mat == 1) ? Ko : Vo;

    __shared__ float x_tile[32][D];
    const int tid = threadIdx.x;
    for (int idx = tid; idx < 32 * D; idx += 256) {
        int r = idx >> 7, c = idx & 127;
        int i = chunk * 32 + r;
        x_tile[r][c] = (i == 0) ? tok[c] : padded[(size_t)s * TT * D + (size_t)(i - 1) * D + c];
    }
    __syncthreads();

    const int c = tid & 127;
    const int rg = tid >> 7;
    const int r0 = rg * 16;
    float acc[16];
    const float bc = bias[c];
#pragma unroll
    for (int r = 0; r < 16; ++r) acc[r] = bc;
    for (int d = 0; d < D; ++d) {
        float wv = W[d * D + c];
#pragma unroll
        for (int r = 0; r < 16; ++r) acc[r] = fmaf(x_tile[r0 + r][d], wv, acc[r]);
    }
    size_t base = (size_t)s * L * D;
    for (int r = 0; r < 16; ++r)
        outp[base + (size_t)(chunk * 32 + r0 + r) * D + c] = acc[r];

    // ---- weight prepack (one block only; stream-serialized before K2/K3) ----
    if (s == 0 && mat == 0 && chunk == 0) {
        if (tid < 64) {
            const int u = tid;
            CW[u * 16 + 0] = Wb1[0 * 64 + u];
            CW[u * 16 + 1] = Wb1[1 * 64 + u];
            CW[u * 16 + 2] = Wb1[2 * 64 + u];
            CW[u * 16 + 3] = Wb1[3 * 64 + u] + Wb1[4 * 64 + u];
            CW[u * 16 + 4] = Wb1[5 * 64 + u];
            CW[u * 16 + 5] = bb1[u];
            CW[u * 16 + 6] = 0.f;
            CW[u * 16 + 7] = 0.f;
#pragma unroll
            for (int k = 0; k < 8; ++k) CW[u * 16 + 8 + k] = Wb2[u * 8 + k];
        }
        if (tid < 128) {
            const int cc = tid;
            RVW[cc * 8 + 0] = Wv1[0 * 128 + cc];
            RVW[cc * 8 + 1] = Wv1[1 * 128 + cc];
            RVW[cc * 8 + 2] = Wv1[2 * 128 + cc];
            RVW[cc * 8 + 3] = Wv1[3 * 128 + cc] + Wv1[4 * 128 + cc];
            RVW[cc * 8 + 4] = Wv1[5 * 128 + cc];
            RVW[cc * 8 + 5] = bv1[cc];
            RVW[cc * 8 + 6] = 0.f;
            RVW[cc * 8 + 7] = 0.f;
        }
        // Wv2 -> B-fragment order for mfma_f32_16x16x32_bf16
        for (int idx = tid; idx < 16384; idx += 256) {
            int f = idx >> 9, r = idx & 511, ln = r >> 3, e = r & 7;
            int kt = f >> 3, ng = f & 7;
            int row = kt * 32 + (ln >> 4) * 8 + e;
            int col = ng * 16 + (ln & 15);
            WV2F[idx] = f2bf(Wv2[(size_t)row * D + col]);
        }
    }
}

// ---------------- K2: logits via MFMA. grid (BN, NH), block 256 (4 waves) ----------------
__global__ __launch_bounds__(256)
void logits_kernel(const float* __restrict__ Q, const float* __restrict__ K,
                   __hip_bfloat16* __restrict__ LW) {
    const int s = blockIdx.x;
    const int h = blockIdx.y;
    const int tid = threadIdx.x;
    const int wv = tid >> 6;
    const int lane = tid & 63;
    const int lrn = lane & 15;
    const int kg = lane >> 4;

    __shared__ float Qs[128][16];
    __shared__ float Ks[128][16];
    for (int e = tid; e < 2048; e += 256) {
        int i = e >> 4, d = e & 15;
        Qs[i][d] = Q[((size_t)s * L + i) * D + h * 16 + d];
        Ks[i][d] = K[((size_t)s * L + i) * D + h * 16 + d];
    }
    __syncthreads();

    // A fragments: 2 M-tiles per wave (rows wv*32 .. wv*32+31); K=32 (d>=16 zero)
    s16x8 afr[2];
#pragma unroll
    for (int m = 0; m < 2; ++m) {
        s16x8 a;
#pragma unroll
        for (int e = 0; e < 8; ++e) a[e] = 0;
        if (kg < 2) {
            const int i = wv * 32 + m * 16 + lrn;
            float4 q0 = *(const float4*)&Qs[i][kg * 8];
            float4 q1 = *(const float4*)&Qs[i][kg * 8 + 4];
            a[0] = (short)f2bf(q0.x); a[1] = (short)f2bf(q0.y);
            a[2] = (short)f2bf(q0.z); a[3] = (short)f2bf(q0.w);
            a[4] = (short)f2bf(q1.x); a[5] = (short)f2bf(q1.y);
            a[6] = (short)f2bf(q1.z); a[7] = (short)f2bf(q1.w);
        }
        afr[m] = a;
    }

    __hip_bfloat16* lw = LW + ((size_t)(s * NH + h) * L) * L;
#pragma unroll
    for (int n = 0; n < 8; ++n) {
        s16x8 b;
#pragma unroll
        for (int e = 0; e < 8; ++e) b[e] = 0;
        if (kg < 2) {
            const int j = n * 16 + lrn;
            float4 k0 = *(const float4*)&Ks[j][kg * 8];
            float4 k1 = *(const float4*)&Ks[j][kg * 8 + 4];
            b[0] = (short)f2bf(k0.x); b[1] = (short)f2bf(k0.y);
            b[2] = (short)f2bf(k0.z); b[3] = (short)f2bf(k0.w);
            b[4] = (short)f2bf(k1.x); b[5] = (short)f2bf(k1.y);
            b[6] = (short)f2bf(k1.z); b[7] = (short)f2bf(k1.w);
        }
#pragma unroll
        for (int m = 0; m < 2; ++m) {
            f32x4 acc = (f32x4){0.f, 0.f, 0.f, 0.f};
            acc = __builtin_amdgcn_mfma_f32_16x16x32_bf16(afr[m], b, acc, 0, 0, 0);
#pragma unroll
            for (int r = 0; r < 4; ++r)
                lw[(size_t)(wv * 32 + m * 16 + kg * 4 + r) * L + n * 16 + lrn] =
                    __float2bfloat16(acc[r] * 0.25f);
        }
    }
}

// ---------------- K3: core per (s,i). grid (L, BN), block 128 (2 waves) ----------------
__global__ __launch_bounds__(128, 3)
void attn_kernel(const float* __restrict__ padded, const int* __restrict__ masks,
                 const float* __restrict__ pos3d,
                 const float* __restrict__ gamma, const float* __restrict__ beta,
                 const float* __restrict__ tok,
                 const float* __restrict__ CW, const float* __restrict__ RVW,
                 const unsigned short* __restrict__ WV2F,
                 const float* __restrict__ bb2, const float* __restrict__ bv2,
                 const float* __restrict__ V, const __hip_bfloat16* __restrict__ LW,
                 float* __restrict__ out) {
    const int i = blockIdx.x;
    const int s = blockIdx.y;
    const int tid = threadIdx.x;
    const int wave = tid >> 6;
    const int lane = tid & 63;
    const int hA = lane & 15;        // mfma A-row / D-col index
    const int kg = lane >> 4;        // mfma k-group

    __shared__ float4 feat4_lds[144];      // idx j + (j>>3): {dx,dy,dz,dist}
    __shared__ float  feat5_lds[L];        // dist2
    __shared__ float  w_lds[NH][132];      // COMPACTED softmax weights [h][rank]
    __shared__ float  gs_lds[NH][132];     // GS rows (f32)
    __shared__ float  a1_part[4][132];
    __shared__ float  a2_lds[D];
    __shared__ float  reds[2][NH];
    __shared__ float  red2[2][2];
    __shared__ unsigned long long kb_lds[2];
    __shared__ int    jmap_lds[128];

    // ---- early loads: logits + mask ----
    __hip_bfloat16 lr8[NH];
#pragma unroll
    for (int hh = 0; hh < NH; ++hh)
        lr8[hh] = LW[((size_t)(s * NH + hh) * L + i) * L + tid];
    const int keep = (tid == 0) ? 1 : masks[(size_t)s * TT + (tid - 1)];

    // ballot for compaction
    const unsigned long long bal = __ballot(keep != 0);
    if (lane == 0) kb_lds[wave] = bal;

    // ---- relative features for pair (i, j=tid) ----
    float pix = 0.f, piy = 0.f, piz = 0.f;
    if (i > 0) { const float* pp = pos3d + ((size_t)s * TT + (i - 1)) * 3; pix = pp[0]; piy = pp[1]; piz = pp[2]; }
    float pjx = 0.f, pjy = 0.f, pjz = 0.f;
    if (tid > 0) { const float* pp = pos3d + ((size_t)s * TT + (tid - 1)) * 3; pjx = pp[0]; pjy = pp[1]; pjz = pp[2]; }
    const float dx = pix - pjx, dy = piy - pjy, dz = piz - pjz;
    const float dist2 = dx * dx + dy * dy + dz * dz;
    const float dist = sqrtf(dist2);
    feat4_lds[tid + (tid >> 3)] = make_float4(dx, dy, dz, dist);
    feat5_lds[tid] = dist2;

    // zero compacted-w array + jmap
    for (int idx = tid; idx < NH * 132; idx += 128) ((float*)w_lds)[idx] = 0.f;
    jmap_lds[tid] = 0;
    __syncthreads();                       // barrier A

    const unsigned long long b0 = kb_lds[0];
    const int nk = __popcll(b0) + __popcll(kb_lds[1]);
    const int NK32 = (nk + 31) >> 5;       // compacted 32-tiles (1..4)
    int rank = 0;
    if (keep) {
        rank = __popcll(bal & ((1ull << lane) - 1)) + (wave ? __popcll(b0) : 0);
        jmap_lds[rank] = tid;
    }

    // ---- rel-bias MLP (wave-uniform scalar loads from CW) ----
    float bias[NH];
#pragma unroll
    for (int hh = 0; hh < NH; ++hh) bias[hh] = 0.f;
    if (i > 0 && tid > 0 && keep) {
        const float4* cw4 = (const float4*)CW;
#pragma unroll 2
        for (int u = 0; u < 64; ++u) {
            float4 wa  = cw4[u * 4 + 0];
            float4 wb  = cw4[u * 4 + 1];
            float4 w2a = cw4[u * 4 + 2];
            float4 w2b = cw4[u * 4 + 3];
            float hv = wb.y;
            hv = fmaf(dx, wa.x, hv);
            hv = fmaf(dy, wa.y, hv);
            hv = fmaf(dz, wa.z, hv);
            hv = fmaf(dist, wa.w, hv);
            hv = fmaf(dist2, wb.x, hv);
            hv = gelu_sig(hv);
            bias[0] = fmaf(hv, w2a.x, bias[0]);
            bias[1] = fmaf(hv, w2a.y, bias[1]);
            bias[2] = fmaf(hv, w2a.z, bias[2]);
            bias[3] = fmaf(hv, w2a.w, bias[3]);
            bias[4] = fmaf(hv, w2b.x, bias[4]);
            bias[5] = fmaf(hv, w2b.y, bias[5]);
            bias[6] = fmaf(hv, w2b.z, bias[6]);
            bias[7] = fmaf(hv, w2b.w, bias[7]);
        }
#pragma unroll
        for (int hh = 0; hh < NH; ++hh) bias[hh] += bb2[hh];
    }

    // ---- softmax (no max subtraction; masked lanes contribute exactly 0) ----
    float p[NH];
#pragma unroll
    for (int hh = 0; hh < NH; ++hh) {
        float lv = __bfloat162float(lr8[hh]) + bias[hh];
        p[hh] = keep ? __expf(lv) : 0.f;
    }
#pragma unroll
    for (int hh = 0; hh < NH; ++hh) {
        float v = p[hh];
        for (int off = 32; off >= 1; off >>= 1) v += __shfl_xor(v, off, 64);
        if (lane == 0) reds[wave][hh] = v;
    }
    __syncthreads();                       // barrier B
    if (keep) {
#pragma unroll
        for (int hh = 0; hh < NH; ++hh) {
            float inv = __builtin_amdgcn_rcpf(reds[0][hh] + reds[1][hh]);
            w_lds[hh][rank] = p[hh] * inv;
        }
    }
    __syncthreads();                       // barrier C: w (compacted) + feat + jmap ready

    // ---- pass 2 ----
    const int jg = tid >> 5;
    const int c0v = (tid & 31) * 4;
    const int h0v = c0v >> 4;
    const int per = NK32 * 8;              // a1 iters per jg group
    const float* Vs = V + (size_t)s * L * D;

    if (i > 0) {
        // per-lane rel-val weights for its 4 fragment columns c = wave*64+n*16+hA
        float rvw[4][6];
#pragma unroll
        for (int n = 0; n < 4; ++n) {
            const int c = wave * 64 + n * 16 + hA;
            float4 ra = *(const float4*)&RVW[(size_t)c * 8 + 0];
            rvw[n][0] = ra.x; rvw[n][1] = ra.y; rvw[n][2] = ra.z; rvw[n][3] = ra.w;
            rvw[n][4] = RVW[(size_t)c * 8 + 4];
            rvw[n][5] = RVW[(size_t)c * 8 + 5];
        }

        f32x4 accG[4];
#pragma unroll
        for (int n = 0; n < 4; ++n) accG[n] = (f32x4){0.f, 0.f, 0.f, 0.f};

        // ---- compacted G + GS via MFMA (NK32 k-tiles) ----
#pragma unroll
        for (int kt = 0; kt < 4; ++kt) {
            if (kt >= NK32) break;
            // A-fragment of compacted W (zero row pad; rank-0 (=j0) slot zeroed)
            s16x8 wf;
#pragma unroll
            for (int e = 0; e < 8; ++e) wf[e] = 0;
            if (hA < NH) {
                const int j0 = kt * 32 + kg * 8;
                float4 wv0 = *(const float4*)&w_lds[hA][j0];
                float4 wv1 = *(const float4*)&w_lds[hA][j0 + 4];
                if (kt == 0 && kg == 0) wv0.x = 0.f;   // exclude j==0 from g-sum
                wf[0] = (short)f2bf(wv0.x); wf[1] = (short)f2bf(wv0.y);
                wf[2] = (short)f2bf(wv0.z); wf[3] = (short)f2bf(wv0.w);
                wf[4] = (short)f2bf(wv1.x); wf[5] = (short)f2bf(wv1.y);
                wf[6] = (short)f2bf(wv1.z); wf[7] = (short)f2bf(wv1.w);
            }
            s16x8 bfr[4];
#pragma unroll
            for (int e = 0; e < 8; ++e) {
                const int jj = jmap_lds[kt * 32 + kg * 8 + e];
                float4 fa = feat4_lds[jj + (jj >> 3)];
                float f5 = feat5_lds[jj];
#pragma unroll
                for (int n = 0; n < 4; ++n) {
                    float hv = rvw[n][5];
                    hv = fmaf(fa.x, rvw[n][0], hv);
                    hv = fmaf(fa.y, rvw[n][1], hv);
                    hv = fmaf(fa.z, rvw[n][2], hv);
                    hv = fmaf(fa.w, rvw[n][3], hv);
                    hv = fmaf(f5,  rvw[n][4], hv);
                    bfr[n][e] = (short)f2bf(gelu_sig(hv));
                }
            }
#pragma unroll
            for (int n = 0; n < 4; ++n)
                accG[n] = __builtin_amdgcn_mfma_f32_16x16x32_bf16(wf, bfr[n], accG[n], 0, 0, 0);
        }

        // ---- a1 over compacted keys ----
        float a1a[4] = {0.f, 0.f, 0.f, 0.f};
        for (int r = 0; r < per; ++r) {
            const int jt = jg * per + r;
            const int jr = jmap_lds[jt];
            float4 vcur = *(const float4*)&Vs[(size_t)jr * D + c0v];
            const float wj = w_lds[h0v][jt];
            a1a[0] = fmaf(wj, vcur.x, a1a[0]);
            a1a[1] = fmaf(wj, vcur.y, a1a[1]);
            a1a[2] = fmaf(wj, vcur.z, a1a[2]);
            a1a[3] = fmaf(wj, vcur.w, a1a[3]);
        }
        *(float4*)&a1_part[jg][c0v] = make_float4(a1a[0], a1a[1], a1a[2], a1a[3]);

        // GS rows 0..7 live in lanes 0..31 (D-layout row=(lane>>4)*4+reg)
        if (lane < 32) {
#pragma unroll
            for (int n = 0; n < 4; ++n)
#pragma unroll
                for (int r = 0; r < 4; ++r)
                    gs_lds[(lane >> 4) * 4 + r][wave * 64 + n * 16 + hA] = accG[n][r];
        }
        __syncthreads();

        // ---- a2 = GS @ Wv2 via MFMA (B prepacked in WV2F) ----
        f32x4 acc2[4];
#pragma unroll
        for (int n = 0; n < 4; ++n) acc2[n] = (f32x4){0.f, 0.f, 0.f, 0.f};
#pragma unroll
        for (int kt = 0; kt < 4; ++kt) {
            s16x8 gf;
#pragma unroll
            for (int e = 0; e < 8; ++e) gf[e] = 0;
            if (hA < NH) {
                const int k0 = kt * 32 + kg * 8;
                float4 g0 = *(const float4*)&gs_lds[hA][k0];
                float4 g1 = *(const float4*)&gs_lds[hA][k0 + 4];
                gf[0] = (short)f2bf(g0.x); gf[1] = (short)f2bf(g0.y);
                gf[2] = (short)f2bf(g0.z); gf[3] = (short)f2bf(g0.w);
                gf[4] = (short)f2bf(g1.x); gf[5] = (short)f2bf(g1.y);
                gf[6] = (short)f2bf(g1.z); gf[7] = (short)f2bf(g1.w);
            }
#pragma unroll
            for (int n = 0; n < 4; ++n) {
                const int f = kt * 8 + wave * 4 + n;
                s16x8 bw = *(const s16x8*)&WV2F[((size_t)f * 64 + lane) * 8];
                acc2[n] = __builtin_amdgcn_mfma_f32_16x16x32_bf16(gf, bw, acc2[n], 0, 0, 0);
            }
        }
#pragma unroll
        for (int n = 0; n < 4; ++n)
            if (kg == wave) a2_lds[wave * 64 + n * 16 + hA] = acc2[n][n];
        __syncthreads();

        // ---- epilogue ----
        const float a1f = a1_part[0][tid] + a1_part[1][tid] + a1_part[2][tid] + a1_part[3][tid];
        const float S1 = 1.0f - w_lds[tid >> 4][0];
        const size_t o = (size_t)s * TT * D + (size_t)(i - 1) * D + tid;
        out[o] = a1f + a2_lds[tid] + S1 * bv2[tid] + padded[o];
    } else {
        // ---- cls row: a2 == 0; V-reduce (compacted) + layernorm ----
        float a1a[4] = {0.f, 0.f, 0.f, 0.f};
        for (int r = 0; r < per; ++r) {
            const int jt = jg * per + r;
            const int jr = jmap_lds[jt];
            float4 vcur = *(const float4*)&Vs[(size_t)jr * D + c0v];
            const float wj = w_lds[h0v][jt];
            a1a[0] = fmaf(wj, vcur.x, a1a[0]);
            a1a[1] = fmaf(wj, vcur.y, a1a[1]);
            a1a[2] = fmaf(wj, vcur.z, a1a[2]);
            a1a[3] = fmaf(wj, vcur.w, a1a[3]);
        }
        *(float4*)&a1_part[jg][c0v] = make_float4(a1a[0], a1a[1], a1a[2], a1a[3]);
        __syncthreads();
        const float a1f = a1_part[0][tid] + a1_part[1][tid] + a1_part[2][tid] + a1_part[3][tid];

        float st = a1f + tok[tid];
        float sum = st, sum2 = st * st;
        for (int off = 32; off >= 1; off >>= 1) {
            sum += __shfl_xor(sum, off, 64);
            sum2 += __shfl_xor(sum2, off, 64);
        }
        if (lane == 0) { red2[wave][0] = sum; red2[wave][1] = sum2; }
        __syncthreads();
        sum = red2[0][0] + red2[1][0];
        sum2 = red2[0][1] + red2[1][1];
        const float mu = sum * (1.0f / 128.0f);
        const float var = sum2 * (1.0f / 128.0f) - mu * mu;
        const float y = (st - mu) * rsqrtf(var + 1e-5f) * gamma[tid] + beta[tid];
        out[(size_t)BN * TT * D + (size_t)s * D + tid] = y;
    }
}

extern "C" void kernel_launch(void* const* d_in, const int* in_sizes, int n_in,
                              void* d_out, int out_size, void* d_ws, size_t ws_size,
                              hipStream_t stream) {
    const float* padded = (const float*)d_in[0];
    const int*   masks  = (const int*)d_in[1];
    const float* pos3d  = (const float*)d_in[2];
    const float* Wq = (const float*)d_in[3];
    const float* bq = (const float*)d_in[4];
    const float* Wk = (const float*)d_in[5];
    const float* bk = (const float*)d_in[6];
    const float* Wv = (const float*)d_in[7];
    const float* bv = (const float*)d_in[8];
    const float* gamma = (const float*)d_in[9];
    const float* beta  = (const float*)d_in[10];
    const float* tok   = (const float*)d_in[11];
    const float* Wb1 = (const float*)d_in[12];
    const float* bb1 = (const float*)d_in[13];
    const float* Wb2 = (const float*)d_in[14];
    const float* bb2 = (const float*)d_in[15];
    const float* Wv1 = (const float*)d_in[16];
    const float* bv1 = (const float*)d_in[17];
    const float* Wv2 = (const float*)d_in[18];
    const float* bv2 = (const float*)d_in[19];
    float* out = (float*)d_out;

    float* Q  = (float*)d_ws;
    float* K  = Q + (size_t)BN * L * D;
    float* Vw = K + (size_t)BN * L * D;
    __hip_bfloat16* LW = (__hip_bfloat16*)(Vw + (size_t)BN * L * D);
    float* CW  = (float*)(LW + (size_t)BN * NH * L * L);
    float* RVW = CW + 64 * 16;
    unsigned short* WV2F = (unsigned short*)(RVW + 128 * 8);

    qkv_kernel<<<dim3(BN, 3, 4), 256, 0, stream>>>(padded, tok, Wq, bq, Wk, bk, Wv, bv,
                                                   Wb1, bb1, Wb2, Wv1, bv1, Wv2,
                                                   Q, K, Vw, CW, RVW, WV2F);
    logits_kernel<<<dim3(BN, NH), 256, 0, stream>>>(Q, K, LW);
    attn_kernel<<<dim3(L, BN), 128, 0, stream>>>(padded, masks, pos3d, gamma, beta, tok,
                                                 CW, RVW, WV2F, bb2, bv2,
                                                 Vw, LW, out);
}